// Round 1
// baseline (294.540 us; speedup 1.0000x reference)
//
#include <hip/hip_runtime.h>

// Problem constants (from reference): B=256 batches, N=128 neurons,
// state dim E = 4N = 512.  Outputs: ydot (B*E) then J (B*E*E), concat flat.
#define BATCH 256
#define NN    128          // neurons
#define EDIM  512          // 4*NN
#define E4    128          // float4 per J row

typedef float vf4 __attribute__((ext_vector_type(4)));

// Kernel 1: per-(batch, neuron) physics.
//  - writes ydot (float4 per (b,i): Vdot, mdot, hdot, ndot)
//  - writes jtab[b*128+i] = (JVV_diag + S, JVm, JVh, JVn)
//  - block 0 additionally writes invC[128] and nitab[3*128] (-1/tau_{m,h,n})
__global__ __launch_bounds__(128) void hh_k1(
    const float* __restrict__ y,     const float* __restrict__ Ic,
    const float* __restrict__ C,     const float* __restrict__ g_Na,
    const float* __restrict__ E_Na,  const float* __restrict__ g_K,
    const float* __restrict__ E_K,   const float* __restrict__ g_L,
    const float* __restrict__ E_L,   const float* __restrict__ m_inf,
    const float* __restrict__ tau_m, const float* __restrict__ h_inf,
    const float* __restrict__ tau_h, const float* __restrict__ n_inf,
    const float* __restrict__ tau_n, const float* __restrict__ g_C,
    float* __restrict__ ydot_out,    float4* __restrict__ jtab,
    float* __restrict__ invC_out,    float* __restrict__ nitab)
{
    __shared__ float sInvC[NN];   // 1/C[j]
    __shared__ float sW[NN];      // V_j / C[j]
    __shared__ float sRed[NN];    // reduction buffer for S

    const int b = blockIdx.x;
    const int i = threadIdx.x;

    // y[b, 4i .. 4i+3] = (V, m, h, n) -- contiguous, coalesced float4
    const float4 yv = ((const float4*)(y + (size_t)b * EDIM))[i];
    const float V = yv.x, m = yv.y, h = yv.z, n = yv.w;

    const float invC = 1.0f / C[i];
    sInvC[i] = invC;
    sW[i]    = V * invC;
    __syncthreads();

    // Two dot products over g_C row i (row is L2-resident, reused by all blocks):
    //   rowS = sum_j g_C[i,j] * invC[j]          (batch-independent)
    //   dotW = sum_j g_C[i,j] * V_j * invC[j]
    // dV[i] = V_i * rowS - dotW
    float rowS = 0.f, dotW = 0.f;
    const float4* grow = (const float4*)(g_C + i * NN);
#pragma unroll 8
    for (int j4 = 0; j4 < NN / 4; ++j4) {
        const float4 g = grow[j4];
        const int j = j4 * 4;
        rowS += g.x * sInvC[j] + g.y * sInvC[j + 1] + g.z * sInvC[j + 2] + g.w * sInvC[j + 3];
        dotW += g.x * sW[j]    + g.y * sW[j + 1]    + g.z * sW[j + 2]    + g.w * sW[j + 3];
    }
    const float dV = V * rowS - dotW;

    // S = sum over ALL i of rowS (reference: jnp.sum(gC_over_C), a scalar)
    sRed[i] = rowS;
    __syncthreads();
    for (int s = NN / 2; s > 0; s >>= 1) {
        if (i < s) sRed[i] += sRed[i + s];
        __syncthreads();
    }
    const float S = sRed[0];

    // HH right-hand side
    const float m2 = m * m, m3 = m2 * m;
    const float n2 = n * n, n3 = n2 * n, n4 = n3 * n;
    const float gna = g_Na[i], ena = E_Na[i];
    const float gk  = g_K[i],  ek  = E_K[i];
    const float gl  = g_L[i],  el  = E_L[i];

    const float Vdot = invC * (-gna * m3 * h * (V - ena)
                               - gk * n4 * (V - ek)
                               - gl * (V - el)
                               + Ic[b]) + dV;
    const float itm = 1.0f / tau_m[i];
    const float ith = 1.0f / tau_h[i];
    const float itn = 1.0f / tau_n[i];
    const float mdot = (m_inf[i] - m) * itm;
    const float hdot = (h_inf[i] - h) * ith;
    const float ndot = (n_inf[i] - n) * itn;

    ((float4*)(ydot_out + (size_t)b * EDIM))[i] = make_float4(Vdot, mdot, hdot, ndot);

    // Jacobian diagonal-block values for this (b,i)
    const float jvv = invC * (-gl - gna * h * m3 - gk * n4) + S;  // add S here once
    const float jvm = -invC * (3.0f * gna * h * m2 * (V - ena));
    const float jvh = -invC * (gna * m3 * (V - ena));
    const float jvn = -invC * (4.0f * gk * n3 * (V - ek));
    jtab[(b << 7) + i] = make_float4(jvv, jvm, jvh, jvn);

    if (b == 0) {
        invC_out[i]        = invC;
        nitab[i]           = -itm;
        nitab[NN + i]      = -ith;
        nitab[2 * NN + i]  = -itn;
    }
}

// Kernel 2: fill J. One float4 (= one (i-row, j-neuron) column group) per thread.
// All index math is shifts/masks; row (a,i,b) is wave-uniform (2 waves per row).
__global__ __launch_bounds__(256) void hh_k2(
    const float4* __restrict__ jtab, const float* __restrict__ invC,
    const float* __restrict__ nitab, const float* __restrict__ g_C,
    vf4* __restrict__ J)
{
    const unsigned idx = blockIdx.x * 256u + threadIdx.x;  // < 16,777,216
    const int c4      = idx & (E4 - 1);        // j (column neuron)
    const unsigned rw = idx >> 7;              // b*512 + r
    const int r       = rw & (EDIM - 1);       // row within batch
    const int b       = rw >> 9;               // batch
    const int a       = r & 3;                 // equation type of the row
    const int i       = r >> 2;                // row neuron

    float v0 = 0.f, v1 = 0.f, v2 = 0.f, v3 = 0.f;
    if (a == 0) {
        // JVV dense part: -g_C[i,j]/C[j], diag gets + (dVdiag + S) and dV/dm,h,n
        const float g = g_C[(i << 7) + c4];
        v0 = -g * invC[c4];
        if (c4 == i) {
            const float4 jv = jtab[(b << 7) + i];
            v0 += jv.x; v1 = jv.y; v2 = jv.z; v3 = jv.w;
        }
    } else if (c4 == i) {
        const float nit = nitab[((a - 1) << 7) + i];
        if (a == 1)      v1 = nit;
        else if (a == 2) v2 = nit;
        else             v3 = nit;
    }
    const vf4 v = {v0, v1, v2, v3};
    __builtin_nontemporal_store(v, &J[idx]);   // streaming store, no reuse
}

extern "C" void kernel_launch(void* const* d_in, const int* in_sizes, int n_in,
                              void* d_out, int out_size, void* d_ws, size_t ws_size,
                              hipStream_t stream) {
    const float* y     = (const float*)d_in[0];
    const float* Ic    = (const float*)d_in[1];
    const float* C     = (const float*)d_in[2];
    const float* g_Na  = (const float*)d_in[3];
    const float* E_Na  = (const float*)d_in[4];
    const float* g_K   = (const float*)d_in[5];
    const float* E_K   = (const float*)d_in[6];
    const float* g_L   = (const float*)d_in[7];
    const float* E_L   = (const float*)d_in[8];
    const float* m_inf = (const float*)d_in[9];
    const float* tau_m = (const float*)d_in[10];
    const float* h_inf = (const float*)d_in[11];
    const float* tau_h = (const float*)d_in[12];
    const float* n_inf = (const float*)d_in[13];
    const float* tau_n = (const float*)d_in[14];
    const float* g_C   = (const float*)d_in[15];

    float* ydot = (float*)d_out;
    vf4*   J    = (vf4*)((float*)d_out + (size_t)BATCH * EDIM);

    // workspace layout: jtab (512 KB) | invC (512 B) | nitab (1.5 KB)
    float4* jtab = (float4*)d_ws;
    float*  invC = (float*)((char*)d_ws + (size_t)BATCH * NN * sizeof(float4));
    float*  nit  = invC + NN;

    hh_k1<<<BATCH, NN, 0, stream>>>(y, Ic, C, g_Na, E_Na, g_K, E_K, g_L, E_L,
                                    m_inf, tau_m, h_inf, tau_h, n_inf, tau_n,
                                    g_C, ydot, jtab, invC, nit);

    const unsigned total4 = (unsigned)BATCH * EDIM * E4;  // 16,777,216
    hh_k2<<<total4 / 256, 256, 0, stream>>>(jtab, invC, nit, g_C, J);
}

// Round 2
// 287.430 us; speedup vs baseline: 1.0247x; 1.0247x over previous
//
#include <hip/hip_runtime.h>

// B=256 batches, N=128 neurons, E = 4N = 512. Out: ydot (B*E) | J (B*E*E).
#define BATCH 256
#define NN    128
#define EDIM  512

typedef float vf4 __attribute__((ext_vector_type(4)));

// ---------------------------------------------------------------------------
// Kernel 1: per-(batch, neuron) physics. Block = one batch, 512 threads:
// thread t -> (i = t>>2, jq = t&3); the 128-wide coupling dot is split 4-way
// and combined with shfl_xor. 8 waves/block, 256 blocks -> 8 waves/CU.
// ---------------------------------------------------------------------------
__global__ __launch_bounds__(512) void hh_k1(
    const float* __restrict__ y,     const float* __restrict__ Ic,
    const float* __restrict__ C,     const float* __restrict__ g_Na,
    const float* __restrict__ E_Na,  const float* __restrict__ g_K,
    const float* __restrict__ E_K,   const float* __restrict__ g_L,
    const float* __restrict__ E_L,   const float* __restrict__ m_inf,
    const float* __restrict__ tau_m, const float* __restrict__ h_inf,
    const float* __restrict__ tau_h, const float* __restrict__ n_inf,
    const float* __restrict__ tau_n, const float* __restrict__ g_C,
    float* __restrict__ ydot_out,    float4* __restrict__ jtab,
    float* __restrict__ invC_out,    float* __restrict__ nitab)
{
    __shared__ float sInvC[NN];
    __shared__ float sW[NN];
    __shared__ float sRed[NN];
    __shared__ float sS;

    const int b  = blockIdx.x;
    const int t  = threadIdx.x;
    const int i  = t >> 2;
    const int jq = t & 3;

    if (t < NN) {
        const float ic = 1.0f / C[t];
        sInvC[t] = ic;
        sW[t] = y[(size_t)b * EDIM + 4 * t] * ic;   // V_j * invC_j
    }
    __syncthreads();

    // Partial dots over j = jq*32 .. jq*32+31 (8 float4 loads, all independent)
    float rowS = 0.f, dotW = 0.f;
    const float4* grow = (const float4*)(g_C + (i << 7) + (jq << 5));
#pragma unroll
    for (int j4 = 0; j4 < 8; ++j4) {
        const float4 g = grow[j4];
        const int j = (jq << 5) + j4 * 4;
        rowS += g.x * sInvC[j] + g.y * sInvC[j + 1] + g.z * sInvC[j + 2] + g.w * sInvC[j + 3];
        dotW += g.x * sW[j]    + g.y * sW[j + 1]    + g.z * sW[j + 2]    + g.w * sW[j + 3];
    }
    // combine the 4 jq-partials (lanes t, t^1, t^2 are in the same wave)
    rowS += __shfl_xor(rowS, 1);  rowS += __shfl_xor(rowS, 2);
    dotW += __shfl_xor(dotW, 1);  dotW += __shfl_xor(dotW, 2);

    if (jq == 0) sRed[i] = rowS;
    __syncthreads();
    if (t < 64) {   // S = sum_i rowS[i]  (reference: jnp.sum(gC_over_C))
        float v = sRed[t] + sRed[t + 64];
        v += __shfl_xor(v, 1);  v += __shfl_xor(v, 2);  v += __shfl_xor(v, 4);
        v += __shfl_xor(v, 8);  v += __shfl_xor(v, 16); v += __shfl_xor(v, 32);
        if (t == 0) sS = v;
    }
    __syncthreads();

    if (jq == 0) {
        const float S = sS;
        const float4 yv = ((const float4*)(y + (size_t)b * EDIM))[i];
        const float V = yv.x, m = yv.y, h = yv.z, n = yv.w;
        const float invC = sInvC[i];
        const float dV = V * rowS - dotW;

        const float m2 = m * m, m3 = m2 * m;
        const float n2 = n * n, n3 = n2 * n, n4 = n3 * n;
        const float gna = g_Na[i], ena = E_Na[i];
        const float gk  = g_K[i],  ek  = E_K[i];
        const float gl  = g_L[i],  el  = E_L[i];

        const float Vdot = invC * (-gna * m3 * h * (V - ena)
                                   - gk * n4 * (V - ek)
                                   - gl * (V - el)
                                   + Ic[b]) + dV;
        const float itm = 1.0f / tau_m[i];
        const float ith = 1.0f / tau_h[i];
        const float itn = 1.0f / tau_n[i];

        ((float4*)(ydot_out + (size_t)b * EDIM))[i] =
            make_float4(Vdot, (m_inf[i] - m) * itm, (h_inf[i] - h) * ith,
                        (n_inf[i] - n) * itn);

        const float jvv = invC * (-gl - gna * h * m3 - gk * n4) + S;
        const float jvm = -invC * (3.0f * gna * h * m2 * (V - ena));
        const float jvh = -invC * (gna * m3 * (V - ena));
        const float jvn = -invC * (4.0f * gk * n3 * (V - ek));
        jtab[(b << 7) + i] = make_float4(jvv, jvm, jvh, jvn);

        if (b == 0) {
            invC_out[i]       = invC;
            nitab[i]          = -itm;
            nitab[NN + i]     = -ith;
            nitab[2 * NN + i] = -itn;
        }
    }
}

// ---------------------------------------------------------------------------
// Kernel 2: fill J. 32 threads per row, 4 float4 (64 B) per thread, plain
// stores. Row mapping puts the same equation-type `a` in every lane of a
// wave: g = a*32768 + b*128 + i  ->  row = b*512 + i*4 + a. Uniform branch.
// ---------------------------------------------------------------------------
__global__ __launch_bounds__(256) void hh_k2(
    const float4* __restrict__ jtab, const float* __restrict__ invC,
    const float* __restrict__ nitab, const float* __restrict__ g_C,
    vf4* __restrict__ J)
{
    const int t = threadIdx.x;
    const int q = t & 31;                               // column sub-index
    const unsigned g = blockIdx.x * 8u + (t >> 5);      // [0, 131072)
    const int a = g >> 15;                              // wave-uniform
    const unsigned s = g & 32767u;
    const int b = s >> 7;
    const int i = s & 127;
    const unsigned row = ((unsigned)b << 9) | ((unsigned)i << 2) | (unsigned)a;

    vf4* __restrict__ Jrow = J + (size_t)row * 128;

    if (a == 0) {
        // diagonal payload (broadcast load, L1-resident)
        const float4 jv = jtab[(b << 7) + i];
#pragma unroll
        for (int k = 0; k < 4; ++k) {
            const int j = q + 32 * k;
            float v0 = -g_C[(i << 7) + j] * invC[j];
            float v1 = 0.f, v2 = 0.f, v3 = 0.f;
            if (j == i) { v0 += jv.x; v1 = jv.y; v2 = jv.z; v3 = jv.w; }
            const vf4 v = {v0, v1, v2, v3};
            Jrow[j] = v;
        }
    } else {
        const float nit = nitab[((a - 1) << 7) + i];
#pragma unroll
        for (int k = 0; k < 4; ++k) {
            const int j = q + 32 * k;
            vf4 v = {0.f, 0.f, 0.f, 0.f};
            if (j == i) {
                if (a == 1)      v.y = nit;
                else if (a == 2) v.z = nit;
                else             v.w = nit;
            }
            Jrow[j] = v;
        }
    }
}

extern "C" void kernel_launch(void* const* d_in, const int* in_sizes, int n_in,
                              void* d_out, int out_size, void* d_ws, size_t ws_size,
                              hipStream_t stream) {
    const float* y     = (const float*)d_in[0];
    const float* Ic    = (const float*)d_in[1];
    const float* C     = (const float*)d_in[2];
    const float* g_Na  = (const float*)d_in[3];
    const float* E_Na  = (const float*)d_in[4];
    const float* g_K   = (const float*)d_in[5];
    const float* E_K   = (const float*)d_in[6];
    const float* g_L   = (const float*)d_in[7];
    const float* E_L   = (const float*)d_in[8];
    const float* m_inf = (const float*)d_in[9];
    const float* tau_m = (const float*)d_in[10];
    const float* h_inf = (const float*)d_in[11];
    const float* tau_h = (const float*)d_in[12];
    const float* n_inf = (const float*)d_in[13];
    const float* tau_n = (const float*)d_in[14];
    const float* g_C   = (const float*)d_in[15];

    float* ydot = (float*)d_out;
    vf4*   J    = (vf4*)((float*)d_out + (size_t)BATCH * EDIM);

    float4* jtab = (float4*)d_ws;
    float*  invC = (float*)((char*)d_ws + (size_t)BATCH * NN * sizeof(float4));
    float*  nit  = invC + NN;

    hh_k1<<<BATCH, 512, 0, stream>>>(y, Ic, C, g_Na, E_Na, g_K, E_K, g_L, E_L,
                                     m_inf, tau_m, h_inf, tau_h, n_inf, tau_n,
                                     g_C, ydot, jtab, invC, nit);

    // 131072 row-groups * 8 per block
    hh_k2<<<131072 / 8, 256, 0, stream>>>(jtab, invC, nit, g_C, J);
}